// Round 1
// baseline (1070.156 us; speedup 1.0000x reference)
//
#include <hip/hip_runtime.h>
#include <hip/hip_bf16.h>
#include <cstdint>
#include <cstddef>

#define NUM_TOK     16384
#define HID         4096
#define NEXP        64
#define TOPK        8
#define TOK_PER_BLK 32
#define KCHUNK      64
#define NWAVE       4

typedef const float __attribute__((address_space(1)))* gptr_t;
typedef float __attribute__((address_space(3)))* lptr_t;

// ---------------- transpose W [E][H] -> Wt [H][E] (1 MiB, ~1us) ----------------
__global__ __launch_bounds__(256) void transpose_w(const float* __restrict__ W,
                                                   float* __restrict__ Wt) {
    int id4 = blockIdx.x * 256 + threadIdx.x;   // 0..65535, one float4 of a W row
    int e   = id4 >> 10;                        // H/4 = 1024 float4 per row
    int k   = (id4 & 1023) << 2;
    float4 w = reinterpret_cast<const float4*>(W)[id4];
    Wt[(size_t)(k + 0) * NEXP + e] = w.x;
    Wt[(size_t)(k + 1) * NEXP + e] = w.y;
    Wt[(size_t)(k + 2) * NEXP + e] = w.z;
    Wt[(size_t)(k + 3) * NEXP + e] = w.w;
}

// ---------------- wave-wide helpers (wave = 64) ----------------
__device__ __forceinline__ float wave_max(float v) {
#pragma unroll
    for (int off = 32; off >= 1; off >>= 1)
        v = fmaxf(v, __shfl_xor(v, off, 64));
    return v;
}
__device__ __forceinline__ float wave_sum(float v) {
#pragma unroll
    for (int off = 32; off >= 1; off >>= 1)
        v += __shfl_xor(v, off, 64);
    return v;
}
__device__ __forceinline__ unsigned long long wave_max_u64(unsigned long long v) {
#pragma unroll
    for (int off = 32; off >= 1; off >>= 1) {
        unsigned long long o = __shfl_xor(v, off, 64);
        v = (o > v) ? o : v;
    }
    return v;
}

// ---------------- main: logits + softmax + top8 + count/importance ----------------
// grid 512, block 256 (4 waves). wave w owns 8 tokens; lane = expert.
__global__ __launch_bounds__(256, 2) void router_main(
    const float* __restrict__ hidden,   // [T][H]
    const float* __restrict__ Wt,       // [H][E]
    float* __restrict__ out_idx,        // [T*8] (indices stored as float)
    float* __restrict__ out_gates,      // [T*8]
    float* __restrict__ gImp,           // [E] fp32 atomic accum
    float* __restrict__ gCnt) {         // [E]
    __shared__ float Bs[KCHUNK * NEXP];        // 16 KiB weight chunk, layout [k][e]
    __shared__ float red_imp[NWAVE][NEXP];
    __shared__ float red_cnt[NWAVE][NEXP];

    const int tid  = threadIdx.x;
    const int lane = tid & 63;
    const int wave = __builtin_amdgcn_readfirstlane(tid >> 6);  // force wave-uniform
    const int tok0 = blockIdx.x * TOK_PER_BLK + wave * 8;

    // wave-uniform token row pointers -> scalar (SMEM) loads in the K loop
    const float* rows[8];
#pragma unroll
    for (int t = 0; t < 8; ++t)
        rows[t] = hidden + (size_t)(tok0 + t) * HID;

    float acc[8];
#pragma unroll
    for (int t = 0; t < 8; ++t) acc[t] = 0.0f;

    for (int c = 0; c < HID / KCHUNK; ++c) {
        // stage 16 KiB of Wt into LDS: 256 thr x 4 x 16B, contiguous lane order
        const float* src = Wt + (size_t)c * KCHUNK * NEXP;
#pragma unroll
        for (int i = 0; i < 4; ++i) {
            int off = (i * 256 + tid) * 4;   // float index, 16B per thread
            __builtin_amdgcn_global_load_lds((gptr_t)(src + off),
                                             (lptr_t)(&Bs[off]), 16, 0, 0);
        }
        __syncthreads();   // drains vmcnt, staging visible

        const int kbase = c * KCHUNK;
        float part[8];     // per-chunk partials: tree-ish accumulation, lower fp error
#pragma unroll
        for (int t = 0; t < 8; ++t) part[t] = 0.0f;

#pragma unroll
        for (int g = 0; g < KCHUNK / 8; ++g) {
            float b[8];
#pragma unroll
            for (int j = 0; j < 8; ++j)
                b[j] = Bs[(g * 8 + j) * NEXP + lane];   // stride-64 dwords: ds_read2st64, conflict-free
#pragma unroll
            for (int t = 0; t < 8; ++t) {
                const float* rp = rows[t] + kbase + g * 8;  // uniform -> s_load_dwordx8
#pragma unroll
                for (int j = 0; j < 8; ++j)
                    part[t] = fmaf(rp[j], b[j], part[t]);   // v_fmac v, s, v
            }
        }
#pragma unroll
        for (int t = 0; t < 8; ++t) acc[t] += part[t];
        __syncthreads();   // readers done before next chunk overwrites Bs
    }

    // ---------------- epilogue: per-token softmax + top-8 ----------------
    float impL = 0.0f, cntL = 0.0f;
#pragma unroll
    for (int t = 0; t < 8; ++t) {
        float v = acc[t];
        float m = wave_max(v);
        float p = expf(v - m);
        float s = wave_sum(p);
        float score = p / s;          // softmax score of (token t, expert lane)
        impL += score;

        // key: score bits (positive float -> monotone in uint) | (63 - e) tie-break
        unsigned long long key =
            ((unsigned long long)__float_as_uint(score) << 32) |
            (unsigned long long)(63 - lane);

        float g[TOPK];
        int   id[TOPK];
#pragma unroll
        for (int r = 0; r < TOPK; ++r) {
            unsigned long long k = wave_max_u64(key);
            int   we = 63 - (int)(unsigned)(k & 0xffffffffULL);
            float wv = __uint_as_float((unsigned)(k >> 32));
            g[r]  = wv;
            id[r] = we;
            if (lane == we) { key = 0ULL; cntL += 1.0f; }
        }
        float gsum = ((g[0] + g[1]) + (g[2] + g[3])) +
                     ((g[4] + g[5]) + (g[6] + g[7])) + 1e-6f;
        if (lane == 0) {
            float inv = 1.0f / gsum;
            int tok = tok0 + t;
            float4 i0 = make_float4((float)id[0], (float)id[1], (float)id[2], (float)id[3]);
            float4 i1 = make_float4((float)id[4], (float)id[5], (float)id[6], (float)id[7]);
            float4 g0 = make_float4(g[0] * inv, g[1] * inv, g[2] * inv, g[3] * inv);
            float4 g1 = make_float4(g[4] * inv, g[5] * inv, g[6] * inv, g[7] * inv);
            *reinterpret_cast<float4*>(out_idx   + (size_t)tok * 8)     = i0;
            *reinterpret_cast<float4*>(out_idx   + (size_t)tok * 8 + 4) = i1;
            *reinterpret_cast<float4*>(out_gates + (size_t)tok * 8)     = g0;
            *reinterpret_cast<float4*>(out_gates + (size_t)tok * 8 + 4) = g1;
        }
    }

    // ---------------- block-level reduce of counts/importance, then atomics ----------------
    red_imp[wave][lane] = impL;
    red_cnt[wave][lane] = cntL;
    __syncthreads();
    if (wave == 0) {
        float a = red_imp[0][lane] + red_imp[1][lane] + red_imp[2][lane] + red_imp[3][lane];
        float b = red_cnt[0][lane] + red_cnt[1][lane] + red_cnt[2][lane] + red_cnt[3][lane];
        atomicAdd(&gImp[lane], a);
        atomicAdd(&gCnt[lane], b);
    }
}

// ---------------- aux loss ----------------
__global__ __launch_bounds__(64) void aux_kernel(const float* __restrict__ gImp,
                                                 const float* __restrict__ gCnt,
                                                 float* __restrict__ out_aux) {
    int lane = threadIdx.x;
    float v = gImp[lane] * gCnt[lane];
    v = wave_sum(v);
    if (lane == 0)
        *out_aux = v * (0.01f / (float)NUM_TOK);   // alpha * mean
}

extern "C" void kernel_launch(void* const* d_in, const int* in_sizes, int n_in,
                              void* d_out, int out_size, void* d_ws, size_t ws_size,
                              hipStream_t stream) {
    const float* hidden = (const float*)d_in[0];   // [4,4096,4096] f32
    const float* W      = (const float*)d_in[1];   // [64,4096] f32

    float* out       = (float*)d_out;
    float* out_idx   = out;                                // 16384*8
    float* out_gates = out + (size_t)NUM_TOK * TOPK;       // 16384*8
    float* out_aux   = out + (size_t)2 * NUM_TOK * TOPK;   // 1

    float* Wt   = (float*)d_ws;                            // 1 MiB
    float* gImp = (float*)((char*)d_ws + (1 << 20));       // 64 f32
    float* gCnt = gImp + NEXP;                             // 64 f32

    hipMemsetAsync(gImp, 0, 2 * NEXP * sizeof(float), stream);
    transpose_w<<<256, 256, 0, stream>>>(W, Wt);
    router_main<<<NUM_TOK / TOK_PER_BLK, 256, 0, stream>>>(hidden, Wt, out_idx,
                                                           out_gates, gImp, gCnt);
    aux_kernel<<<1, 64, 0, stream>>>(gImp, gCnt, out_aux);
}

// Round 4
// 875.014 us; speedup vs baseline: 1.2230x; 1.2230x over previous
//
#include <hip/hip_runtime.h>
#include <hip/hip_bf16.h>
#include <cstdint>
#include <cstddef>

#define NUM_TOK     16384
#define HID         4096
#define NEXP        64
#define TOPK        8
#define NT          8               // tokens per wave
#define TOK_PER_BLK 32              // 4 waves * 8
#define KCHUNK      64
#define NCHUNK      (HID / KCHUNK)  // 64  (same chunking as the passing R1)
#define NWAVE       4

typedef const float __attribute__((address_space(1)))* gptr_t;
typedef float __attribute__((address_space(3)))* lptr_t;

// ---------------- transpose W [E][H] -> Wt [H][E] (1 MiB) ----------------
__global__ __launch_bounds__(256) void transpose_w(const float* __restrict__ W,
                                                   float* __restrict__ Wt) {
    int id4 = blockIdx.x * 256 + threadIdx.x;
    int e   = id4 >> 10;
    int k   = (id4 & 1023) << 2;
    float4 w = reinterpret_cast<const float4*>(W)[id4];
    Wt[(size_t)(k + 0) * NEXP + e] = w.x;
    Wt[(size_t)(k + 1) * NEXP + e] = w.y;
    Wt[(size_t)(k + 2) * NEXP + e] = w.z;
    Wt[(size_t)(k + 3) * NEXP + e] = w.w;
}

// ---------------- wave-wide helpers (wave = 64) ----------------
__device__ __forceinline__ float wave_max(float v) {
#pragma unroll
    for (int off = 32; off >= 1; off >>= 1)
        v = fmaxf(v, __shfl_xor(v, off, 64));
    return v;
}
__device__ __forceinline__ float wave_sum(float v) {
#pragma unroll
    for (int off = 32; off >= 1; off >>= 1)
        v += __shfl_xor(v, off, 64);
    return v;
}
__device__ __forceinline__ unsigned long long wave_max_u64(unsigned long long v) {
#pragma unroll
    for (int off = 32; off >= 1; off >>= 1) {
        unsigned long long o = __shfl_xor(v, off, 64);
        v = (o > v) ? o : v;
    }
    return v;
}

// ---------------- main ----------------
// grid 512, block 256 (4 waves). lane = expert; wave owns 8 tokens.
// X: wave-uniform global_load_dwordx4 (vector path, L1 broadcast) — NOT s_load,
//    NOT LDS (both measured dead ends: R1 scalar 825us, R3 LDS-broadcast ~4x amp).
// W: LDS [k][e] double-buffered via global_load_lds; one dword per k, reused
//    across 8 tokens. Accumulation order bit-identical to the passing R1:
//    64-k chunk partials, k-ascending fmaf, acc += part per chunk.
__global__ __launch_bounds__(256, 2) void router_main(
    const float* __restrict__ hidden,   // [T][H]
    const float* __restrict__ Wt,       // [H][E]
    float* __restrict__ out_idx,        // [T*8]
    float* __restrict__ out_gates,      // [T*8]
    float* __restrict__ gImp,           // [E]
    float* __restrict__ gCnt) {         // [E]
    __shared__ __align__(16) float Ws[2][KCHUNK * NEXP];   // 2 x 16 KiB
    __shared__ float red_imp[NWAVE][NEXP];
    __shared__ float red_cnt[NWAVE][NEXP];

    const int tid  = threadIdx.x;
    const int lane = tid & 63;
    const int wave = __builtin_amdgcn_readfirstlane(tid >> 6);
    const int tok0 = blockIdx.x * TOK_PER_BLK + wave * NT;

    // pin a zero into a VGPR so x addresses can't be proven uniform -> no s_load
    int vzero = 0;
    asm volatile("" : "+v"(vzero));

    auto stageW = [&](int c) {
        const float* wsrc = Wt + (size_t)c * KCHUNK * NEXP;
        float* dst = &Ws[c & 1][0];
#pragma unroll
        for (int i = 0; i < 4; ++i) {
            int lin = (i * 256 + tid) * 4;   // float index, 16B per thread
            __builtin_amdgcn_global_load_lds((gptr_t)(wsrc + lin),
                                             (lptr_t)(dst + lin), 16, 0, 0);
        }
    };

    float acc[NT];
#pragma unroll
    for (int t = 0; t < NT; ++t) acc[t] = 0.0f;

    stageW(0);
    for (int c = 0; c < NCHUNK; ++c) {
        __syncthreads();                  // drains stage(c); also fences buf reuse
        if (c + 1 < NCHUNK) stageW(c + 1);
        const float* __restrict__ wb = &Ws[c & 1][0];

        float part[NT];
#pragma unroll
        for (int t = 0; t < NT; ++t) part[t] = 0.0f;

#pragma unroll
        for (int k4 = 0; k4 < KCHUNK / 4; ++k4) {
            // 8 wave-uniform 16B vector loads (lane-equal address => 1 request)
            float4 x4[NT];
            const int off = c * KCHUNK + k4 * 4 + vzero;   // VGPR offset
#pragma unroll
            for (int t = 0; t < NT; ++t) {
                const float* rowt = hidden + (size_t)(tok0 + t) * HID;
                x4[t] = *reinterpret_cast<const float4*>(rowt + off);
            }
            float w0 = wb[(k4 * 4 + 0) * NEXP + lane];
            float w1 = wb[(k4 * 4 + 1) * NEXP + lane];
            float w2 = wb[(k4 * 4 + 2) * NEXP + lane];
            float w3 = wb[(k4 * 4 + 3) * NEXP + lane];
#pragma unroll
            for (int t = 0; t < NT; ++t) {
                // strictly k-ascending chain: bit-identical to R1's order
                part[t] = fmaf(x4[t].x, w0, part[t]);
                part[t] = fmaf(x4[t].y, w1, part[t]);
                part[t] = fmaf(x4[t].z, w2, part[t]);
                part[t] = fmaf(x4[t].w, w3, part[t]);
            }
        }
#pragma unroll
        for (int t = 0; t < NT; ++t) acc[t] += part[t];
    }

    // ---------------- epilogue (identical to passing R1) ----------------
    float impL = 0.0f, cntL = 0.0f;
#pragma unroll
    for (int t = 0; t < NT; ++t) {
        float v = acc[t];
        float m = wave_max(v);
        float p = expf(v - m);
        float s = wave_sum(p);
        float score = p / s;
        impL += score;

        unsigned long long key =
            ((unsigned long long)__float_as_uint(score) << 32) |
            (unsigned long long)(63 - lane);

        float g[TOPK];
        int   id[TOPK];
#pragma unroll
        for (int r = 0; r < TOPK; ++r) {
            unsigned long long k = wave_max_u64(key);
            int   we = 63 - (int)(unsigned)(k & 0xffffffffULL);
            float wv = __uint_as_float((unsigned)(k >> 32));
            g[r]  = wv;
            id[r] = we;
            if (lane == we) { key = 0ULL; cntL += 1.0f; }
        }
        float gsum = ((g[0] + g[1]) + (g[2] + g[3])) +
                     ((g[4] + g[5]) + (g[6] + g[7])) + 1e-6f;
        if (lane == 0) {
            float inv = 1.0f / gsum;
            int tok = tok0 + t;
            float4 i0 = make_float4((float)id[0], (float)id[1], (float)id[2], (float)id[3]);
            float4 i1 = make_float4((float)id[4], (float)id[5], (float)id[6], (float)id[7]);
            float4 g0 = make_float4(g[0] * inv, g[1] * inv, g[2] * inv, g[3] * inv);
            float4 g1 = make_float4(g[4] * inv, g[5] * inv, g[6] * inv, g[7] * inv);
            *reinterpret_cast<float4*>(out_idx   + (size_t)tok * 8)     = i0;
            *reinterpret_cast<float4*>(out_idx   + (size_t)tok * 8 + 4) = i1;
            *reinterpret_cast<float4*>(out_gates + (size_t)tok * 8)     = g0;
            *reinterpret_cast<float4*>(out_gates + (size_t)tok * 8 + 4) = g1;
        }
    }

    red_imp[wave][lane] = impL;
    red_cnt[wave][lane] = cntL;
    __syncthreads();
    if (wave == 0) {
        float a = red_imp[0][lane] + red_imp[1][lane] + red_imp[2][lane] + red_imp[3][lane];
        float b = red_cnt[0][lane] + red_cnt[1][lane] + red_cnt[2][lane] + red_cnt[3][lane];
        atomicAdd(&gImp[lane], a);
        atomicAdd(&gCnt[lane], b);
    }
}

// ---------------- aux loss ----------------
__global__ __launch_bounds__(64) void aux_kernel(const float* __restrict__ gImp,
                                                 const float* __restrict__ gCnt,
                                                 float* __restrict__ out_aux) {
    int lane = threadIdx.x;
    float v = gImp[lane] * gCnt[lane];
    v = wave_sum(v);
    if (lane == 0)
        *out_aux = v * (0.01f / (float)NUM_TOK);
}

extern "C" void kernel_launch(void* const* d_in, const int* in_sizes, int n_in,
                              void* d_out, int out_size, void* d_ws, size_t ws_size,
                              hipStream_t stream) {
    const float* hidden = (const float*)d_in[0];   // [4,4096,4096] f32
    const float* W      = (const float*)d_in[1];   // [64,4096] f32

    float* out       = (float*)d_out;
    float* out_idx   = out;
    float* out_gates = out + (size_t)NUM_TOK * TOPK;
    float* out_aux   = out + (size_t)2 * NUM_TOK * TOPK;

    float* Wt   = (float*)d_ws;                       // 1 MiB
    float* gImp = (float*)((char*)d_ws + (1 << 20));  // 64 f32
    float* gCnt = gImp + NEXP;                        // 64 f32

    hipMemsetAsync(gImp, 0, 2 * NEXP * sizeof(float), stream);
    transpose_w<<<256, 256, 0, stream>>>(W, Wt);
    router_main<<<NUM_TOK / TOK_PER_BLK, 256, 0, stream>>>(hidden, Wt, out_idx,
                                                           out_gates, gImp, gCnt);
    aux_kernel<<<1, 64, 0, stream>>>(gImp, gCnt, out_aux);
}

// Round 5
// 512.993 us; speedup vs baseline: 2.0861x; 1.7057x over previous
//
#include <hip/hip_runtime.h>
#include <cstdint>
#include <cstddef>

#define NUM_TOK 16384
#define HID     4096
#define NEXP    64
#define TOPK    8

typedef const float __attribute__((address_space(1)))* gptr_t;
typedef float __attribute__((address_space(3)))* lptr_t;

// ---------------- transpose W [E][H] -> Wt [H][E] (1 MiB) ----------------
__global__ __launch_bounds__(256) void transpose_w(const float* __restrict__ W,
                                                   float* __restrict__ Wt) {
    int id4 = blockIdx.x * 256 + threadIdx.x;
    int e   = id4 >> 10;
    int k   = (id4 & 1023) << 2;
    float4 w = reinterpret_cast<const float4*>(W)[id4];
    Wt[(size_t)(k + 0) * NEXP + e] = w.x;
    Wt[(size_t)(k + 1) * NEXP + e] = w.y;
    Wt[(size_t)(k + 2) * NEXP + e] = w.z;
    Wt[(size_t)(k + 3) * NEXP + e] = w.w;
}

__device__ __forceinline__ float wave_sum(float v) {
#pragma unroll
    for (int off = 32; off >= 1; off >>= 1)
        v += __shfl_xor(v, off, 64);
    return v;
}

// ---------------- main GEMM: lane = token, W wave-uniform via SGPR ----------------
// grid (256, ksplit), block 256 (4 waves = 4 expert-quarters of the same 64 tokens).
// X staged coalesced into LDS (global_load_lds, 256B/row-chunk), read per-lane
// ds_read_b64 stride 66. W read wave-uniform -> s_load (1 MiB, L2-resident).
// Partials out in [slice][e][t] layout (coalesced store + coalesced finalize read).
__global__ __launch_bounds__(256, 4) void router_main(
    const float* __restrict__ hidden,   // [T][H]
    const float* __restrict__ Wt,       // [H][E]
    float* __restrict__ partial,        // [ksplit][E][T]
    int nchunks) {                      // 64-k chunks per slice
    __shared__ __align__(16) float Xs[2][64 * 66];   // 33 KB, stride 66 floats

    const int tid  = threadIdx.x;
    const int lane = tid & 63;
    const int wave = __builtin_amdgcn_readfirstlane(tid >> 6);
    const int T0   = blockIdx.x * 64;
    const int s    = blockIdx.y;
    const int k0   = s * nchunks * 64;
    const int q16  = wave * 16;

    auto stage = [&](int c) {
        int buf = c & 1;
#pragma unroll
        for (int j = 0; j < 16; ++j) {
            int r = wave * 16 + j;     // each wave stages 16 token rows
            const float* src = hidden + (size_t)(T0 + r) * HID + k0 + c * 64 + lane;
            __builtin_amdgcn_global_load_lds((gptr_t)src,
                                             (lptr_t)(&Xs[buf][r * 66 + lane]), 4, 0, 0);
        }
    };

    float acc[16];
#pragma unroll
    for (int i = 0; i < 16; ++i) acc[i] = 0.0f;

    stage(0);
    for (int c = 0; c < nchunks; ++c) {
        __syncthreads();                  // drains stage(c); fences buffer reuse
        if (c + 1 < nchunks) stage(c + 1);
        const float* __restrict__ xrow = &Xs[c & 1][lane * 66];
        const float* __restrict__ wp   = Wt + (size_t)(k0 + c * 64) * NEXP + q16; // uniform

        float part[16];
#pragma unroll
        for (int i = 0; i < 16; ++i) part[i] = 0.0f;

#pragma unroll
        for (int k4 = 0; k4 < 16; ++k4) {
            float2 xa = *reinterpret_cast<const float2*>(xrow + k4 * 4);      // ds_read_b64
            float2 xb = *reinterpret_cast<const float2*>(xrow + k4 * 4 + 2);  // ds_read_b64
#pragma unroll
            for (int i = 0; i < 16; ++i) {
                float w0 = wp[(k4 * 4 + 0) * NEXP + i];   // uniform -> s_load
                float w1 = wp[(k4 * 4 + 1) * NEXP + i];
                float w2 = wp[(k4 * 4 + 2) * NEXP + i];
                float w3 = wp[(k4 * 4 + 3) * NEXP + i];
                // k-ascending chain per (token, expert): R1-proven numerics
                part[i] = fmaf(xa.x, w0, part[i]);
                part[i] = fmaf(xa.y, w1, part[i]);
                part[i] = fmaf(xb.x, w2, part[i]);
                part[i] = fmaf(xb.y, w3, part[i]);
            }
        }
#pragma unroll
        for (int i = 0; i < 16; ++i) acc[i] += part[i];   // two-level sum
    }

    float* pp = partial + (size_t)(s * NEXP + q16) * NUM_TOK + T0 + lane;
#pragma unroll
    for (int i = 0; i < 16; ++i) pp[(size_t)i * NUM_TOK] = acc[i];   // coalesced
}

// ---------------- finalize: per-lane softmax + top-8 over 64 regs ----------------
// grid 64, block 256. Thread t owns token t: all 64 logits in registers.
__global__ __launch_bounds__(256) void finalize(
    const float* __restrict__ partial, int nslice,
    float* __restrict__ out_idx, float* __restrict__ out_gates,
    float* __restrict__ gImp, float* __restrict__ gCnt) {
    __shared__ float red_imp[4][NEXP];
    __shared__ float red_cnt[4][NEXP];

    const int tid  = threadIdx.x;
    const int lane = tid & 63;
    const int wave = tid >> 6;
    const int t    = blockIdx.x * 256 + tid;

    float sc[NEXP];
#pragma unroll
    for (int e = 0; e < NEXP; ++e) {
        float v = partial[(size_t)e * NUM_TOK + t];       // coalesced (t = lane-contig)
        for (int s2 = 1; s2 < nslice; ++s2)
            v += partial[(size_t)(s2 * NEXP + e) * NUM_TOK + t];  // fixed order
        sc[e] = v;
    }

    float m = sc[0];
#pragma unroll
    for (int e = 1; e < NEXP; ++e) m = fmaxf(m, sc[e]);
    float sum = 0.0f;
#pragma unroll
    for (int e = 0; e < NEXP; ++e) { sc[e] = expf(sc[e] - m); sum += sc[e]; }
#pragma unroll
    for (int e = 0; e < NEXP; ++e) sc[e] = sc[e] / sum;   // softmax scores

    // top-8: masked argmax, strict '>', ascending e => lowest index on ties
    unsigned long long used = 0ull;
    float g[TOPK];
    float fid[TOPK];
#pragma unroll
    for (int r = 0; r < TOPK; ++r) {
        float best = -1.0f;
        int   bi   = 0;
#pragma unroll
        for (int e = 0; e < NEXP; ++e) {
            bool ok = (((used >> e) & 1ull) == 0ull) && (sc[e] > best);
            best = ok ? sc[e] : best;
            bi   = ok ? e : bi;
        }
        used |= (1ull << bi);
        g[r]   = best;
        fid[r] = (float)bi;
    }
    float gsum = ((g[0] + g[1]) + (g[2] + g[3])) +
                 ((g[4] + g[5]) + (g[6] + g[7])) + 1e-6f;
    float inv = 1.0f / gsum;

    float4 i0 = make_float4(fid[0], fid[1], fid[2], fid[3]);
    float4 i1 = make_float4(fid[4], fid[5], fid[6], fid[7]);
    float4 g0 = make_float4(g[0] * inv, g[1] * inv, g[2] * inv, g[3] * inv);
    float4 g1 = make_float4(g[4] * inv, g[5] * inv, g[6] * inv, g[7] * inv);
    *reinterpret_cast<float4*>(out_idx   + (size_t)t * 8)     = i0;
    *reinterpret_cast<float4*>(out_idx   + (size_t)t * 8 + 4) = i1;
    *reinterpret_cast<float4*>(out_gates + (size_t)t * 8)     = g0;
    *reinterpret_cast<float4*>(out_gates + (size_t)t * 8 + 4) = g1;

    // importance (sum of scores per expert) + counts, cross-lane per e
    float myImp = 0.0f, myCnt = 0.0f;
#pragma unroll
    for (int e = 0; e < NEXP; ++e) {
        float se = wave_sum(sc[e]);
        unsigned long long b = __ballot((used >> e) & 1ull);
        if (lane == e) { myImp = se; myCnt = (float)__popcll(b); }
    }
    red_imp[wave][lane] = myImp;
    red_cnt[wave][lane] = myCnt;
    __syncthreads();
    if (wave == 0) {
        float a = red_imp[0][lane] + red_imp[1][lane] + red_imp[2][lane] + red_imp[3][lane];
        float b = red_cnt[0][lane] + red_cnt[1][lane] + red_cnt[2][lane] + red_cnt[3][lane];
        atomicAdd(&gImp[lane], a);
        atomicAdd(&gCnt[lane], b);
    }
}

// ---------------- aux loss ----------------
__global__ __launch_bounds__(64) void aux_kernel(const float* __restrict__ gImp,
                                                 const float* __restrict__ gCnt,
                                                 float* __restrict__ out_aux) {
    int lane = threadIdx.x;
    float v = gImp[lane] * gCnt[lane];
    v = wave_sum(v);
    if (lane == 0)
        *out_aux = v * (0.01f / (float)NUM_TOK);
}

extern "C" void kernel_launch(void* const* d_in, const int* in_sizes, int n_in,
                              void* d_out, int out_size, void* d_ws, size_t ws_size,
                              hipStream_t stream) {
    const float* hidden = (const float*)d_in[0];   // [4,4096,4096] f32
    const float* W      = (const float*)d_in[1];   // [64,4096] f32

    float* out       = (float*)d_out;
    float* out_idx   = out;
    float* out_gates = out + (size_t)NUM_TOK * TOPK;
    float* out_aux   = out + (size_t)2 * NUM_TOK * TOPK;

    float* Wt      = (float*)d_ws;                          // 1 MiB
    float* gImp    = (float*)((char*)d_ws + (1 << 20));     // 64 f32
    float* gCnt    = gImp + NEXP;
    float* partial = (float*)((char*)d_ws + (1 << 20) + 512);

    // choose K-split from available workspace (constant across calls)
    const size_t base = (1u << 20) + 512;
    const size_t per_slice = (size_t)NEXP * NUM_TOK * sizeof(float);  // 4 MiB
    int ksplit = 1;
    if      (ws_size >= base + 4 * per_slice) ksplit = 4;
    else if (ws_size >= base + 2 * per_slice) ksplit = 2;
    const int nchunks = 64 / ksplit;

    hipMemsetAsync(gImp, 0, 2 * NEXP * sizeof(float), stream);
    transpose_w<<<256, 256, 0, stream>>>(W, Wt);
    router_main<<<dim3(256, ksplit), 256, 0, stream>>>(hidden, Wt, partial, nchunks);
    finalize<<<NUM_TOK / 256, 256, 0, stream>>>(partial, ksplit, out_idx, out_gates,
                                                gImp, gCnt);
    aux_kernel<<<1, 64, 0, stream>>>(gImp, gCnt, out_aux);
}